// Round 2
// 825.457 us; speedup vs baseline: 1.0333x; 1.0333x over previous
//
#include <hip/hip_runtime.h>
#include <hip/hip_bf16.h>

#define T_TOK 4096
#define DIM   1024
#define FDIM  4096
#define NEXP  8
// stageB tile (unchanged m97 structure)
#define BM    128
#define BN    128
#define BK    32
// stageA 4-deep pipelined tile
#define AM    256
#define AK    32

typedef __attribute__((ext_vector_type(8))) short bf16x8_t;   // 8 bf16 = 4 VGPR
typedef __attribute__((ext_vector_type(4))) float f32x4_t;    // MFMA C/D

// async global->LDS, 16B per lane; LDS dest = wave-uniform base + lane*16
#define GLD16(gp, lp) __builtin_amdgcn_global_load_lds( \
    (const __attribute__((address_space(1))) unsigned int*)(gp), \
    (__attribute__((address_space(3))) unsigned int*)(lp), 16, 0, 0)

__device__ __forceinline__ unsigned short f2bf(float f) {
    union { __hip_bfloat16 h; unsigned short u; } c;
    c.h = __float2bfloat16(f);
    return c.u;
}
__device__ __forceinline__ uint4 pack8(const float4& a, const float4& b) {
    union { unsigned short s[8]; uint4 v; } u;
    u.s[0] = f2bf(a.x); u.s[1] = f2bf(a.y); u.s[2] = f2bf(a.z); u.s[3] = f2bf(a.w);
    u.s[4] = f2bf(b.x); u.s[5] = f2bf(b.y); u.s[6] = f2bf(b.z); u.s[7] = f2bf(b.w);
    return u.v;
}

// ---------------------------------------------------------------------------
// 0. fp32 -> bf16 streaming convert (8 elems/thread)
// ---------------------------------------------------------------------------
__global__ __launch_bounds__(256) void convert_kernel(
    const float* __restrict__ src, unsigned short* __restrict__ dst, int n8)
{
    int i = blockIdx.x * 256 + threadIdx.x;
    if (i < n8) {
        const float4* s = reinterpret_cast<const float4*>(src) + (size_t)i * 2;
        float4 a = s[0], b = s[1];
        reinterpret_cast<uint4*>(dst)[i] = pack8(a, b);
    }
}

// ---------------------------------------------------------------------------
// 1. Gate: one wave per token. fp32 logits, top-2, renormalized weights.
// ---------------------------------------------------------------------------
__global__ __launch_bounds__(256) void gate_kernel(
    const float* __restrict__ x, const float* __restrict__ gw,
    const float* __restrict__ gb, int* __restrict__ cnt,
    int* __restrict__ toklist, float* __restrict__ wlist)
{
    const int lane = threadIdx.x & 63;
    const int wv   = threadIdx.x >> 6;
    const int t    = blockIdx.x * 4 + wv;
    const float* xr = x + (size_t)t * DIM;

    float4 xv[4];
#pragma unroll
    for (int c = 0; c < 4; ++c)
        xv[c] = *reinterpret_cast<const float4*>(xr + c * 256 + lane * 4);

    float logit[NEXP];
#pragma unroll
    for (int e = 0; e < NEXP; ++e) {
        const float* gr = gw + e * DIM;
        float s = 0.f;
#pragma unroll
        for (int c = 0; c < 4; ++c) {
            float4 g = *reinterpret_cast<const float4*>(gr + c * 256 + lane * 4);
            s += xv[c].x * g.x + xv[c].y * g.y + xv[c].z * g.z + xv[c].w * g.w;
        }
#pragma unroll
        for (int o = 32; o > 0; o >>= 1) s += __shfl_xor(s, o, 64);
        logit[e] = s + gb[e];
    }

    if (lane == 0) {
        int i1 = 0;
#pragma unroll
        for (int e = 1; e < NEXP; ++e) if (logit[e] > logit[i1]) i1 = e;
        int i2 = (i1 == 0) ? 1 : 0;
#pragma unroll
        for (int e = 0; e < NEXP; ++e)
            if (e != i1 && e != i2 && logit[e] > logit[i2]) i2 = e;
        float eb = expf(logit[i2] - logit[i1]);
        float wA = 1.f / (1.f + eb);
        float wB = eb / (1.f + eb);
        int p = atomicAdd(&cnt[i1], 1);
        toklist[i1 * T_TOK + p] = t; wlist[i1 * T_TOK + p] = wA;
        p = atomicAdd(&cnt[i2], 1);
        toklist[i2 * T_TOK + p] = t; wlist[i2 * T_TOK + p] = wB;
    }
}

// ---------------------------------------------------------------------------
// 2. 256-aligned exclusive prefix of per-expert counts (stageA tile = 256)
// ---------------------------------------------------------------------------
__global__ void offsets_kernel(const int* __restrict__ cnt, int* __restrict__ offs)
{
    if (threadIdx.x == 0) {
        int o = 0;
#pragma unroll
        for (int e = 0; e < NEXP; ++e) {
            offs[e] = o;
            o += ((cnt[e] + AM - 1) / AM) * AM;
        }
    }
}

// ---------------------------------------------------------------------------
// 3. Stage A: fused h1/h3 GEMM + SwiGLU -> act (bf16)
//    4-deep pipeline: 256 rows x (128 w1-cols + 128 w3-cols), BK=32,
//    512 thr / 8 waves (2M x 4N), 4 STATIC LDS buffers (128 KB),
//    counted vmcnt(8), 2-bit XOR swizzle, setprio around MFMA clusters.
//    A-operand gathered straight from token-order xb via toklist.
// ---------------------------------------------------------------------------
// LDS buffer layout (shorts), per buffer of 16384 (32 KB):
//   A  : 16 subtiles (16 rows x 32 k, 512 shorts) @ 0
//   B1 :  8 subtiles                              @ 8192
//   B3 :  8 subtiles                              @ 12288
// swizzle within subtile: phys = (row*32 + k) ^ (((row>>1)&3)<<3)
// read (conflict-free b128): swz = (r*32 + quad*8) ^ (((r>>1)&3)<<3)
// staging inverse: lane l -> row (l>>2)&15, kbase ((l0^l3)<<3)|((l1^l4)<<4)

#define KSTEP(T, PF, VM)                                                       \
  {                                                                            \
    const int buf_ = (T) & 3;                                                  \
    const unsigned short* Ab_  = lds + buf_ * 16384 + wm * 4096 + swz;         \
    const unsigned short* Bb1_ = lds + buf_ * 16384 + 8192 + wnn * 1024 + swz; \
    bf16x8_t af_[8], bf_[2];                                                   \
    _Pragma("unroll")                                                          \
    for (int i_ = 0; i_ < 8; ++i_)                                             \
      af_[i_] = *reinterpret_cast<const bf16x8_t*>(Ab_ + i_ * 512);            \
    bf_[0] = *reinterpret_cast<const bf16x8_t*>(Bb1_);                         \
    bf_[1] = *reinterpret_cast<const bf16x8_t*>(Bb1_ + 512);                   \
    if (PF) {                                                                  \
      const int pb_ = ((T) + 3) & 3;                                           \
      GLD16(Ag0 + ((T) + 3) * AK, lds + pb_ * 16384 + wv * 512);               \
      GLD16(Ag1 + ((T) + 3) * AK, lds + pb_ * 16384 + (wv + 8) * 512);         \
    }                                                                          \
    __builtin_amdgcn_s_barrier();                                              \
    asm volatile("s_waitcnt lgkmcnt(0)" ::: "memory");                         \
    __builtin_amdgcn_sched_barrier(0);                                         \
    __builtin_amdgcn_s_setprio(1);                                             \
    _Pragma("unroll")                                                          \
    for (int j_ = 0; j_ < 2; ++j_)                                             \
      _Pragma("unroll")                                                        \
      for (int i_ = 0; i_ < 8; ++i_)                                           \
        acc1[i_][j_] = __builtin_amdgcn_mfma_f32_16x16x32_bf16(                \
            af_[i_], bf_[j_], acc1[i_][j_], 0, 0, 0);                          \
    __builtin_amdgcn_s_setprio(0);                                             \
    __builtin_amdgcn_s_barrier();                                              \
    bf_[0] = *reinterpret_cast<const bf16x8_t*>(Bb1_ + 4096);                  \
    bf_[1] = *reinterpret_cast<const bf16x8_t*>(Bb1_ + 4096 + 512);            \
    if (PF) {                                                                  \
      const int pb_ = ((T) + 3) & 3;                                           \
      GLD16(B1g + ((T) + 3) * AK, lds + pb_ * 16384 + 8192 + wv * 512);        \
      GLD16(B3g + ((T) + 3) * AK, lds + pb_ * 16384 + 12288 + wv * 512);       \
    }                                                                          \
    asm volatile("s_waitcnt " VM ::: "memory");                                \
    __builtin_amdgcn_s_barrier();                                              \
    asm volatile("s_waitcnt lgkmcnt(0)" ::: "memory");                         \
    __builtin_amdgcn_sched_barrier(0);                                         \
    __builtin_amdgcn_s_setprio(1);                                             \
    _Pragma("unroll")                                                          \
    for (int j_ = 0; j_ < 2; ++j_)                                             \
      _Pragma("unroll")                                                        \
      for (int i_ = 0; i_ < 8; ++i_)                                           \
        acc3[i_][j_] = __builtin_amdgcn_mfma_f32_16x16x32_bf16(                \
            af_[i_], bf_[j_], acc3[i_][j_], 0, 0, 0);                          \
    __builtin_amdgcn_s_setprio(0);                                             \
    __builtin_amdgcn_s_barrier();                                              \
  }

__global__ __launch_bounds__(512, 2) void stageA_kernel(
    const unsigned short* __restrict__ xb, const unsigned short* __restrict__ w1b,
    const unsigned short* __restrict__ w3b, const int* __restrict__ cnt,
    const int* __restrict__ offs, const int* __restrict__ toklist,
    const unsigned short* __restrict__ zbuf, unsigned short* __restrict__ act)
{
    const int e  = blockIdx.z;
    const int c  = cnt[e];
    const int mt = blockIdx.y;
    if (mt * AM >= c) return;
    const int nt = blockIdx.x;               // 0..31: 128-col group of F
    const int n0 = nt * 128;

    __shared__ __align__(16) unsigned short lds[4 * 16384];  // 128 KB static

    const int tid  = threadIdx.x;
    const int lane = tid & 63;
    const int wv   = tid >> 6;               // 0..7
    const int wm   = wv >> 2;                // 0..1: 128-row half
    const int wnn  = wv & 3;                 // 0..3: 32-col group
    const int quad = lane >> 4;
    const int r    = lane & 15;

    // conflict-free read swizzle (shorts within subtile)
    const int swz = (r * 32 + quad * 8) ^ (((r >> 1) & 3) << 3);

    // staging lane map = inverse of the swizzle (lane l fills subtile bytes l*16)
    const int wr = (lane >> 2) & 15;
    const int wc = (((lane ^ (lane >> 3)) & 1) << 3) |
                   ((((lane >> 1) ^ (lane >> 4)) & 1) << 4);

    const int stRow = wv * 16 + wr;          // 0..127
    const int ar0 = mt * AM + stRow;         // expert-local row, A subtile wv
    const int ar1 = ar0 + 128;               // A subtile wv+8
    const unsigned short* Ag0 = (ar0 < c)
        ? xb + (size_t)toklist[e * T_TOK + ar0] * DIM + wc : zbuf + wc;
    const unsigned short* Ag1 = (ar1 < c)
        ? xb + (size_t)toklist[e * T_TOK + ar1] * DIM + wc : zbuf + wc;
    const unsigned short* B1g = w1b + ((size_t)e * FDIM + n0 + stRow) * DIM + wc;
    const unsigned short* B3g = w3b + ((size_t)e * FDIM + n0 + stRow) * DIM + wc;

    f32x4_t acc1[8][2], acc3[8][2];
#pragma unroll
    for (int i = 0; i < 8; ++i)
#pragma unroll
        for (int j = 0; j < 2; ++j) {
            acc1[i][j] = (f32x4_t){0.f, 0.f, 0.f, 0.f};
            acc3[i][j] = (f32x4_t){0.f, 0.f, 0.f, 0.f};
        }

    // prologue: stage K-tiles 0..2 (12 GLD16 in flight per wave)
#pragma unroll
    for (int t = 0; t < 3; ++t) {
        GLD16(Ag0 + t * AK, lds + t * 16384 + wv * 512);
        GLD16(Ag1 + t * AK, lds + t * 16384 + (wv + 8) * 512);
        GLD16(B1g + t * AK, lds + t * 16384 + 8192 + wv * 512);
        GLD16(B3g + t * AK, lds + t * 16384 + 12288 + wv * 512);
    }
    asm volatile("s_waitcnt vmcnt(8)" ::: "memory");   // tile 0 landed
    __builtin_amdgcn_s_barrier();

    // main loop: DIM/AK = 32 K-steps; prefetch t+3; counted vmcnt, never 0
#pragma unroll 1
    for (int t = 0; t < 28; ++t) KSTEP(t, 1, "vmcnt(8)");
    KSTEP(28, 1, "vmcnt(8)");
    KSTEP(29, 0, "vmcnt(4)");
    KSTEP(30, 0, "vmcnt(0)");
    KSTEP(31, 0, "vmcnt(0)");

    // epilogue: SwiGLU fuse + bf16 store
    const size_t slot0 = (size_t)offs[e] + (size_t)mt * AM;
    unsigned short* abase = act + (slot0 + wm * 128 + quad * 4) * (size_t)FDIM
                          + n0 + wnn * 32 + r;
#pragma unroll
    for (int i = 0; i < 8; ++i)
#pragma unroll
        for (int j = 0; j < 2; ++j)
#pragma unroll
            for (int rr = 0; rr < 4; ++rr) {
                float h1 = acc1[i][j][rr];
                float h3 = acc3[i][j][rr];
                float sw = h1 / (1.f + __expf(-h1)) * h3;
                abase[(size_t)(i * 16 + rr) * FDIM + j * 16] = f2bf(sw);
            }
}

// ---------------------------------------------------------------------------
// 4. Stage B: out[tok] += cw * (act[slot] @ w2[e]^T)
//    m97 structure, 128x128 tile, K split in 2, atomic combine epilogue.
// ---------------------------------------------------------------------------
__global__ __launch_bounds__(256, 3) void stageB_kernel(
    const unsigned short* __restrict__ act, const unsigned short* __restrict__ w2b,
    const int* __restrict__ cnt, const int* __restrict__ offs,
    const int* __restrict__ toklist, const float* __restrict__ wlist,
    float* __restrict__ out)
{
    const int e  = blockIdx.z & 7;
    const int ks = blockIdx.z >> 3;
    const int c  = cnt[e];
    const int mt = blockIdx.y;
    if (mt * BM >= c) return;
    const int nt = blockIdx.x;               // 0..7 (D/128)
    const size_t slot0 = (size_t)offs[e] + (size_t)mt * BM;
    const int n0 = nt * BN;
    const int kbase = ks * (FDIM / 2);

    __shared__ __align__(16) unsigned short As[BM * BK];    // 8 KB
    __shared__ __align__(16) unsigned short Bs[BN * BK];    // 8 KB

    const int tid  = threadIdx.x;
    const int lane = tid & 63;
    const int wv   = tid >> 6;
    const int wm   = (wv & 1) * 64;
    const int wn   = (wv >> 1) * 64;
    const int quad = lane >> 4;
    const int r    = lane & 15;

    const int dRow = wv * 32 + (lane >> 2);
    const unsigned short* Adma = act + (slot0 + dRow) * FDIM + kbase + (lane & 3) * 8;
    const unsigned short* Bdma = w2b + ((size_t)e * DIM + n0 + dRow) * FDIM + kbase + (lane & 3) * 8;
    const int lds0 = (wv * 32) * BK;
    const int lds1 = (wv * 32 + 16) * BK;

    f32x4_t acc[4][4];
#pragma unroll
    for (int i = 0; i < 4; ++i)
#pragma unroll
        for (int j = 0; j < 4; ++j) acc[i][j] = (f32x4_t){0.f, 0.f, 0.f, 0.f};

    for (int kd = 0; kd < FDIM / 2; kd += BK) {
        __syncthreads();
        GLD16(Adma + kd,             &As[lds0]);
        GLD16(Adma + kd + 16 * FDIM, &As[lds1]);
        GLD16(Bdma + kd,             &Bs[lds0]);
        GLD16(Bdma + kd + 16 * FDIM, &Bs[lds1]);
        __syncthreads();

        bf16x8_t af[4];
#pragma unroll
        for (int i = 0; i < 4; ++i)
            af[i] = *reinterpret_cast<const bf16x8_t*>(&As[(wm + i * 16 + r) * BK + quad * 8]);
#pragma unroll
        for (int j = 0; j < 4; ++j) {
            bf16x8_t bf = *reinterpret_cast<const bf16x8_t*>(&Bs[(wn + j * 16 + r) * BK + quad * 8]);
#pragma unroll
            for (int i = 0; i < 4; ++i)
                acc[i][j] = __builtin_amdgcn_mfma_f32_16x16x32_bf16(af[i], bf, acc[i][j], 0, 0, 0);
        }
    }

    const int row0 = mt * BM;
#pragma unroll
    for (int i = 0; i < 4; ++i)
#pragma unroll
        for (int rr = 0; rr < 4; ++rr) {
            int m = wm + i * 16 + quad * 4 + rr;
            int row = row0 + m;
            if (row < c) {
                int tok  = toklist[e * T_TOK + row];
                float wt = wlist[e * T_TOK + row];
                float* orow = out + (size_t)tok * DIM + n0;
#pragma unroll
                for (int j = 0; j < 4; ++j) {
                    int n = wn + j * 16 + r;
                    atomicAdd(&orow[n], wt * acc[i][j][rr]);
                }
            }
        }
}

// ---------------------------------------------------------------------------
extern "C" void kernel_launch(void* const* d_in, const int* in_sizes, int n_in,
                              void* d_out, int out_size, void* d_ws, size_t ws_size,
                              hipStream_t stream)
{
    (void)in_sizes; (void)n_in; (void)out_size; (void)ws_size;
    const float* x  = (const float*)d_in[0];
    const float* gw = (const float*)d_in[1];
    const float* gb = (const float*)d_in[2];
    const float* w1 = (const float*)d_in[3];
    const float* w3 = (const float*)d_in[4];
    const float* w2 = (const float*)d_in[5];
    float* out = (float*)d_out;

    // ws layout (~294 MB)
    char* ws = (char*)d_ws;
    unsigned short* xb   = (unsigned short*)ws;                        //  8,388,608  (4096x1024 bf16)
    unsigned short* act  = (unsigned short*)(ws + 8388608);            // 83,886,080  (10240x4096 bf16)
    unsigned short* w1b  = (unsigned short*)(ws + 92274688);           // 67,108,864
    unsigned short* w3b  = (unsigned short*)(ws + 159383552);          // 67,108,864
    unsigned short* w2b  = (unsigned short*)(ws + 226492416);          // 67,108,864
    unsigned short* zbuf = (unsigned short*)(ws + 293601280);          //      4,096  (zero page)
    int*   cnt     = (int*)(ws + 293605376);
    int*   offs    = cnt + 64;
    int*   toklist = cnt + 128;
    float* wlist   = (float*)(cnt + 128 + NEXP * T_TOK);

    hipMemsetAsync(cnt, 0, 64, stream);
    hipMemsetAsync(zbuf, 0, 4096, stream);
    hipMemsetAsync(out, 0, (size_t)T_TOK * DIM * sizeof(float), stream);

    const int n8 = NEXP * FDIM * DIM / 8;   // 4,194,304 per weight tensor
    convert_kernel<<<n8 / 256, 256, 0, stream>>>(w1, w1b, n8);
    convert_kernel<<<n8 / 256, 256, 0, stream>>>(w3, w3b, n8);
    convert_kernel<<<n8 / 256, 256, 0, stream>>>(w2, w2b, n8);
    convert_kernel<<<(T_TOK * DIM / 8) / 256, 256, 0, stream>>>(x, xb, T_TOK * DIM / 8);

    gate_kernel<<<T_TOK / 4, 256, 0, stream>>>(x, gw, gb, cnt, toklist, wlist);
    offsets_kernel<<<1, 64, 0, stream>>>(cnt, offs);
    stageA_kernel<<<dim3(FDIM / 128, T_TOK / AM, NEXP), 512, 0, stream>>>(
        xb, w1b, w3b, cnt, offs, toklist, zbuf, act);
    stageB_kernel<<<dim3(DIM / BN, T_TOK / BM, NEXP * 2), 256, 0, stream>>>(
        act, w2b, cnt, offs, toklist, wlist, out);
}

// Round 3
// 822.711 us; speedup vs baseline: 1.0367x; 1.0033x over previous
//
#include <hip/hip_runtime.h>
#include <hip/hip_bf16.h>

#define T_TOK 4096
#define DIM   1024
#define FDIM  4096
#define NEXP  8
// stageB tile (unchanged m97 structure)
#define BM    128
#define BN    128
#define BK    32
// stageA 4-deep pipelined tile
#define AM    256
#define AK    32

typedef __attribute__((ext_vector_type(8))) short bf16x8_t;   // 8 bf16 = 4 VGPR
typedef __attribute__((ext_vector_type(4))) float f32x4_t;    // MFMA C/D

// async global->LDS, 16B per lane; LDS dest = wave-uniform base + lane*16
#define GLD16(gp, lp) __builtin_amdgcn_global_load_lds( \
    (const __attribute__((address_space(1))) unsigned int*)(gp), \
    (__attribute__((address_space(3))) unsigned int*)(lp), 16, 0, 0)

__device__ __forceinline__ unsigned short f2bf(float f) {
    union { __hip_bfloat16 h; unsigned short u; } c;
    c.h = __float2bfloat16(f);
    return c.u;
}
__device__ __forceinline__ uint4 pack8(const float4& a, const float4& b) {
    union { unsigned short s[8]; uint4 v; } u;
    u.s[0] = f2bf(a.x); u.s[1] = f2bf(a.y); u.s[2] = f2bf(a.z); u.s[3] = f2bf(a.w);
    u.s[4] = f2bf(b.x); u.s[5] = f2bf(b.y); u.s[6] = f2bf(b.z); u.s[7] = f2bf(b.w);
    return u.v;
}

// ---------------------------------------------------------------------------
// 0. fp32 -> bf16 streaming convert (8 elems/thread)
// ---------------------------------------------------------------------------
__global__ __launch_bounds__(256) void convert_kernel(
    const float* __restrict__ src, unsigned short* __restrict__ dst, int n8)
{
    int i = blockIdx.x * 256 + threadIdx.x;
    if (i < n8) {
        const float4* s = reinterpret_cast<const float4*>(src) + (size_t)i * 2;
        float4 a = s[0], b = s[1];
        reinterpret_cast<uint4*>(dst)[i] = pack8(a, b);
    }
}

// ---------------------------------------------------------------------------
// 1. Gate: one wave per token. fp32 logits, top-2, renormalized weights.
// ---------------------------------------------------------------------------
__global__ __launch_bounds__(256) void gate_kernel(
    const float* __restrict__ x, const float* __restrict__ gw,
    const float* __restrict__ gb, int* __restrict__ cnt,
    int* __restrict__ toklist, float* __restrict__ wlist)
{
    const int lane = threadIdx.x & 63;
    const int wv   = threadIdx.x >> 6;
    const int t    = blockIdx.x * 4 + wv;
    const float* xr = x + (size_t)t * DIM;

    float4 xv[4];
#pragma unroll
    for (int c = 0; c < 4; ++c)
        xv[c] = *reinterpret_cast<const float4*>(xr + c * 256 + lane * 4);

    float logit[NEXP];
#pragma unroll
    for (int e = 0; e < NEXP; ++e) {
        const float* gr = gw + e * DIM;
        float s = 0.f;
#pragma unroll
        for (int c = 0; c < 4; ++c) {
            float4 g = *reinterpret_cast<const float4*>(gr + c * 256 + lane * 4);
            s += xv[c].x * g.x + xv[c].y * g.y + xv[c].z * g.z + xv[c].w * g.w;
        }
#pragma unroll
        for (int o = 32; o > 0; o >>= 1) s += __shfl_xor(s, o, 64);
        logit[e] = s + gb[e];
    }

    if (lane == 0) {
        int i1 = 0;
#pragma unroll
        for (int e = 1; e < NEXP; ++e) if (logit[e] > logit[i1]) i1 = e;
        int i2 = (i1 == 0) ? 1 : 0;
#pragma unroll
        for (int e = 0; e < NEXP; ++e)
            if (e != i1 && e != i2 && logit[e] > logit[i2]) i2 = e;
        float eb = expf(logit[i2] - logit[i1]);
        float wA = 1.f / (1.f + eb);
        float wB = eb / (1.f + eb);
        int p = atomicAdd(&cnt[i1], 1);
        toklist[i1 * T_TOK + p] = t; wlist[i1 * T_TOK + p] = wA;
        p = atomicAdd(&cnt[i2], 1);
        toklist[i2 * T_TOK + p] = t; wlist[i2 * T_TOK + p] = wB;
    }
}

// ---------------------------------------------------------------------------
// 2. 256-aligned exclusive prefix of per-expert counts (stageA tile = 256)
// ---------------------------------------------------------------------------
__global__ void offsets_kernel(const int* __restrict__ cnt, int* __restrict__ offs)
{
    if (threadIdx.x == 0) {
        int o = 0;
#pragma unroll
        for (int e = 0; e < NEXP; ++e) {
            offs[e] = o;
            o += ((cnt[e] + AM - 1) / AM) * AM;
        }
    }
}

// ---------------------------------------------------------------------------
// 3. Stage A: fused h1/h3 GEMM + SwiGLU -> act (bf16)
//    Single-barrier pipelined K-loop:
//      - A-fragments register-double-buffered one K-step ahead
//      - bf (B1/B3) read same-step; only they gate the MFMA cluster,
//        so LDS latency hides under the 32-MFMA stream (no lgkmcnt(0))
//      - GLD prefetch 3 tiles ahead, counted vmcnt(4), 1 barrier/K-step
//    4 STATIC LDS buffers (128 KB), 2-bit XOR swizzle (0 bank conflicts).
// ---------------------------------------------------------------------------
// LDS buffer layout (shorts), per buffer of 16384 (32 KB):
//   A  : 16 subtiles (16 rows x 32 k, 512 shorts) @ 0
//   B1 :  8 subtiles                              @ 8192
//   B3 :  8 subtiles                              @ 12288
// swizzle within subtile: phys = (row*32 + k) ^ (((row>>1)&3)<<3)
// read (conflict-free b128): swz = (r*32 + quad*8) ^ (((r>>1)&3)<<3)
// staging inverse: lane l -> row (l>>2)&15, kbase ((l0^l3)<<3)|((l1^l4)<<4)

// ASTEP(TC, AFC, AFN, PF, RDNEXT, VM):
//   TC: current K-step index; AFC: current A-frag set (in regs);
//   AFN: next A-frag set (filled this step); PF: issue GLD for tile TC+3;
//   RDNEXT: read AFN; VM: vmcnt string at step end.
#define ASTEP(TC, AFC, AFN, PF, RDNEXT, VM)                                    \
  {                                                                            \
    const unsigned short* bufc_ = lds + ((TC) & 3) * 16384;                    \
    bf16x8_t b1a_ = *reinterpret_cast<const bf16x8_t*>(bufc_ + 8192  + wnn * 1024 + swz);       \
    bf16x8_t b1b_ = *reinterpret_cast<const bf16x8_t*>(bufc_ + 8192  + wnn * 1024 + 512 + swz); \
    bf16x8_t b3a_ = *reinterpret_cast<const bf16x8_t*>(bufc_ + 12288 + wnn * 1024 + swz);       \
    bf16x8_t b3b_ = *reinterpret_cast<const bf16x8_t*>(bufc_ + 12288 + wnn * 1024 + 512 + swz); \
    if (RDNEXT) {                                                              \
      const unsigned short* bufn_ = lds + (((TC) + 1) & 3) * 16384 + wm * 4096 + swz; \
      _Pragma("unroll")                                                        \
      for (int i_ = 0; i_ < 8; ++i_)                                           \
        AFN[i_] = *reinterpret_cast<const bf16x8_t*>(bufn_ + i_ * 512);        \
    }                                                                          \
    __builtin_amdgcn_sched_barrier(0);                                         \
    if (PF) {                                                                  \
      const int pb_ = ((TC) + 3) & 3;                                          \
      GLD16(Ag0 + ((TC) + 3) * AK, lds + pb_ * 16384 + wv * 512);              \
      GLD16(Ag1 + ((TC) + 3) * AK, lds + pb_ * 16384 + (wv + 8) * 512);        \
      GLD16(B1g + ((TC) + 3) * AK, lds + pb_ * 16384 + 8192 + wv * 512);       \
      GLD16(B3g + ((TC) + 3) * AK, lds + pb_ * 16384 + 12288 + wv * 512);      \
    }                                                                          \
    __builtin_amdgcn_s_setprio(1);                                             \
    _Pragma("unroll")                                                          \
    for (int i_ = 0; i_ < 8; ++i_) {                                           \
      acc1[i_][0] = __builtin_amdgcn_mfma_f32_16x16x32_bf16(AFC[i_], b1a_, acc1[i_][0], 0, 0, 0); \
      acc1[i_][1] = __builtin_amdgcn_mfma_f32_16x16x32_bf16(AFC[i_], b1b_, acc1[i_][1], 0, 0, 0); \
      acc3[i_][0] = __builtin_amdgcn_mfma_f32_16x16x32_bf16(AFC[i_], b3a_, acc3[i_][0], 0, 0, 0); \
      acc3[i_][1] = __builtin_amdgcn_mfma_f32_16x16x32_bf16(AFC[i_], b3b_, acc3[i_][1], 0, 0, 0); \
    }                                                                          \
    __builtin_amdgcn_s_setprio(0);                                             \
    asm volatile("s_waitcnt " VM ::: "memory");                                \
    __builtin_amdgcn_s_barrier();                                              \
  }

__global__ __launch_bounds__(512, 2) void stageA_kernel(
    const unsigned short* __restrict__ xb, const unsigned short* __restrict__ w1b,
    const unsigned short* __restrict__ w3b, const int* __restrict__ cnt,
    const int* __restrict__ offs, const int* __restrict__ toklist,
    const unsigned short* __restrict__ zbuf, unsigned short* __restrict__ act)
{
    const int e  = blockIdx.z;
    const int c  = cnt[e];
    const int mt = blockIdx.y;
    if (mt * AM >= c) return;
    const int nt = blockIdx.x;               // 0..31: 128-col group of F
    const int n0 = nt * 128;

    __shared__ __align__(16) unsigned short lds[4 * 16384];  // 128 KB static

    const int tid  = threadIdx.x;
    const int lane = tid & 63;
    const int wv   = tid >> 6;               // 0..7
    const int wm   = wv >> 2;                // 0..1: 128-row half
    const int wnn  = wv & 3;                 // 0..3: 32-col group
    const int quad = lane >> 4;
    const int r    = lane & 15;

    // conflict-free read swizzle (shorts within subtile)
    const int swz = (r * 32 + quad * 8) ^ (((r >> 1) & 3) << 3);

    // staging lane map = inverse of the swizzle
    const int wr = (lane >> 2) & 15;
    const int wc = (((lane ^ (lane >> 3)) & 1) << 3) |
                   ((((lane >> 1) ^ (lane >> 4)) & 1) << 4);

    const int stRow = wv * 16 + wr;          // 0..127
    const int ar0 = mt * AM + stRow;         // expert-local row, A subtile wv
    const int ar1 = ar0 + 128;               // A subtile wv+8
    const unsigned short* Ag0 = (ar0 < c)
        ? xb + (size_t)toklist[e * T_TOK + ar0] * DIM + wc : zbuf + wc;
    const unsigned short* Ag1 = (ar1 < c)
        ? xb + (size_t)toklist[e * T_TOK + ar1] * DIM + wc : zbuf + wc;
    const unsigned short* B1g = w1b + ((size_t)e * FDIM + n0 + stRow) * DIM + wc;
    const unsigned short* B3g = w3b + ((size_t)e * FDIM + n0 + stRow) * DIM + wc;

    f32x4_t acc1[8][2], acc3[8][2];
#pragma unroll
    for (int i = 0; i < 8; ++i)
#pragma unroll
        for (int j = 0; j < 2; ++j) {
            acc1[i][j] = (f32x4_t){0.f, 0.f, 0.f, 0.f};
            acc3[i][j] = (f32x4_t){0.f, 0.f, 0.f, 0.f};
        }

    // prologue: stage K-tiles 0..2 (12 GLD16 in flight per wave)
#pragma unroll
    for (int t = 0; t < 3; ++t) {
        GLD16(Ag0 + t * AK, lds + t * 16384 + wv * 512);
        GLD16(Ag1 + t * AK, lds + t * 16384 + (wv + 8) * 512);
        GLD16(B1g + t * AK, lds + t * 16384 + 8192 + wv * 512);
        GLD16(B3g + t * AK, lds + t * 16384 + 12288 + wv * 512);
    }
    asm volatile("s_waitcnt vmcnt(4)" ::: "memory");   // tiles 0,1 landed
    __builtin_amdgcn_s_barrier();

    // preload A-frag set for tile 0 (compiler inserts lgkm wait before use)
    bf16x8_t afA[8], afB[8];
    {
        const unsigned short* b0 = lds + wm * 4096 + swz;
#pragma unroll
        for (int i = 0; i < 8; ++i)
            afA[i] = *reinterpret_cast<const bf16x8_t*>(b0 + i * 512);
    }

    // main loop: 32 K-steps; per step: bf reads (same tile) + af-next reads,
    // 32 MFMA on previous af set, GLD t+3, vmcnt(4), ONE barrier.
#pragma unroll 1
    for (int t = 0; t < 28; t += 2) {
        ASTEP(t,     afA, afB, 1, 1, "vmcnt(4)");
        ASTEP(t + 1, afB, afA, 1, 1, "vmcnt(4)");
    }
    ASTEP(28, afA, afB, 1, 1, "vmcnt(4)");
    ASTEP(29, afB, afA, 0, 1, "vmcnt(0)");
    ASTEP(30, afA, afB, 0, 1, "vmcnt(0)");
    ASTEP(31, afB, afA, 0, 0, "vmcnt(0)");

    // epilogue: SwiGLU fuse + bf16 store
    const size_t slot0 = (size_t)offs[e] + (size_t)mt * AM;
    unsigned short* abase = act + (slot0 + wm * 128 + quad * 4) * (size_t)FDIM
                          + n0 + wnn * 32 + r;
#pragma unroll
    for (int i = 0; i < 8; ++i)
#pragma unroll
        for (int j = 0; j < 2; ++j)
#pragma unroll
            for (int rr = 0; rr < 4; ++rr) {
                float h1 = acc1[i][j][rr];
                float h3 = acc3[i][j][rr];
                float sw = h1 / (1.f + __expf(-h1)) * h3;
                abase[(size_t)(i * 16 + rr) * FDIM + j * 16] = f2bf(sw);
            }
}

// ---------------------------------------------------------------------------
// 4. Stage B: out[tok] += cw * (act[slot] @ w2[e]^T)
//    m97 structure, 128x128 tile, K split in 2, atomic combine epilogue.
// ---------------------------------------------------------------------------
__global__ __launch_bounds__(256, 3) void stageB_kernel(
    const unsigned short* __restrict__ act, const unsigned short* __restrict__ w2b,
    const int* __restrict__ cnt, const int* __restrict__ offs,
    const int* __restrict__ toklist, const float* __restrict__ wlist,
    float* __restrict__ out)
{
    const int e  = blockIdx.z & 7;
    const int ks = blockIdx.z >> 3;
    const int c  = cnt[e];
    const int mt = blockIdx.y;
    if (mt * BM >= c) return;
    const int nt = blockIdx.x;               // 0..7 (D/128)
    const size_t slot0 = (size_t)offs[e] + (size_t)mt * BM;
    const int n0 = nt * BN;
    const int kbase = ks * (FDIM / 2);

    __shared__ __align__(16) unsigned short As[BM * BK];    // 8 KB
    __shared__ __align__(16) unsigned short Bs[BN * BK];    // 8 KB

    const int tid  = threadIdx.x;
    const int lane = tid & 63;
    const int wv   = tid >> 6;
    const int wm   = (wv & 1) * 64;
    const int wn   = (wv >> 1) * 64;
    const int quad = lane >> 4;
    const int r    = lane & 15;

    const int dRow = wv * 32 + (lane >> 2);
    const unsigned short* Adma = act + (slot0 + dRow) * FDIM + kbase + (lane & 3) * 8;
    const unsigned short* Bdma = w2b + ((size_t)e * DIM + n0 + dRow) * FDIM + kbase + (lane & 3) * 8;
    const int lds0 = (wv * 32) * BK;
    const int lds1 = (wv * 32 + 16) * BK;

    f32x4_t acc[4][4];
#pragma unroll
    for (int i = 0; i < 4; ++i)
#pragma unroll
        for (int j = 0; j < 4; ++j) acc[i][j] = (f32x4_t){0.f, 0.f, 0.f, 0.f};

    for (int kd = 0; kd < FDIM / 2; kd += BK) {
        __syncthreads();
        GLD16(Adma + kd,             &As[lds0]);
        GLD16(Adma + kd + 16 * FDIM, &As[lds1]);
        GLD16(Bdma + kd,             &Bs[lds0]);
        GLD16(Bdma + kd + 16 * FDIM, &Bs[lds1]);
        __syncthreads();

        bf16x8_t af[4];
#pragma unroll
        for (int i = 0; i < 4; ++i)
            af[i] = *reinterpret_cast<const bf16x8_t*>(&As[(wm + i * 16 + r) * BK + quad * 8]);
#pragma unroll
        for (int j = 0; j < 4; ++j) {
            bf16x8_t bf = *reinterpret_cast<const bf16x8_t*>(&Bs[(wn + j * 16 + r) * BK + quad * 8]);
#pragma unroll
            for (int i = 0; i < 4; ++i)
                acc[i][j] = __builtin_amdgcn_mfma_f32_16x16x32_bf16(af[i], bf, acc[i][j], 0, 0, 0);
        }
    }

    const int row0 = mt * BM;
#pragma unroll
    for (int i = 0; i < 4; ++i)
#pragma unroll
        for (int rr = 0; rr < 4; ++rr) {
            int m = wm + i * 16 + quad * 4 + rr;
            int row = row0 + m;
            if (row < c) {
                int tok  = toklist[e * T_TOK + row];
                float wt = wlist[e * T_TOK + row];
                float* orow = out + (size_t)tok * DIM + n0;
#pragma unroll
                for (int j = 0; j < 4; ++j) {
                    int n = wn + j * 16 + r;
                    atomicAdd(&orow[n], wt * acc[i][j][rr]);
                }
            }
        }
}

// ---------------------------------------------------------------------------
extern "C" void kernel_launch(void* const* d_in, const int* in_sizes, int n_in,
                              void* d_out, int out_size, void* d_ws, size_t ws_size,
                              hipStream_t stream)
{
    (void)in_sizes; (void)n_in; (void)out_size; (void)ws_size;
    const float* x  = (const float*)d_in[0];
    const float* gw = (const float*)d_in[1];
    const float* gb = (const float*)d_in[2];
    const float* w1 = (const float*)d_in[3];
    const float* w3 = (const float*)d_in[4];
    const float* w2 = (const float*)d_in[5];
    float* out = (float*)d_out;

    // ws layout (~294 MB)
    char* ws = (char*)d_ws;
    unsigned short* xb   = (unsigned short*)ws;                        //  8,388,608  (4096x1024 bf16)
    unsigned short* act  = (unsigned short*)(ws + 8388608);            // 83,886,080  (10240x4096 bf16)
    unsigned short* w1b  = (unsigned short*)(ws + 92274688);           // 67,108,864
    unsigned short* w3b  = (unsigned short*)(ws + 159383552);          // 67,108,864
    unsigned short* w2b  = (unsigned short*)(ws + 226492416);          // 67,108,864
    unsigned short* zbuf = (unsigned short*)(ws + 293601280);          //      4,096  (zero page)
    int*   cnt     = (int*)(ws + 293605376);
    int*   offs    = cnt + 64;
    int*   toklist = cnt + 128;
    float* wlist   = (float*)(cnt + 128 + NEXP * T_TOK);

    hipMemsetAsync(cnt, 0, 64, stream);
    hipMemsetAsync(zbuf, 0, 4096, stream);
    hipMemsetAsync(out, 0, (size_t)T_TOK * DIM * sizeof(float), stream);

    const int n8 = NEXP * FDIM * DIM / 8;   // 4,194,304 per weight tensor
    convert_kernel<<<n8 / 256, 256, 0, stream>>>(w1, w1b, n8);
    convert_kernel<<<n8 / 256, 256, 0, stream>>>(w3, w3b, n8);
    convert_kernel<<<n8 / 256, 256, 0, stream>>>(w2, w2b, n8);
    convert_kernel<<<(T_TOK * DIM / 8) / 256, 256, 0, stream>>>(x, xb, T_TOK * DIM / 8);

    gate_kernel<<<T_TOK / 4, 256, 0, stream>>>(x, gw, gb, cnt, toklist, wlist);
    offsets_kernel<<<1, 64, 0, stream>>>(cnt, offs);
    stageA_kernel<<<dim3(FDIM / 128, T_TOK / AM, NEXP), 512, 0, stream>>>(
        xb, w1b, w3b, cnt, offs, toklist, zbuf, act);
    stageB_kernel<<<dim3(DIM / BN, T_TOK / BM, NEXP * 2), 256, 0, stream>>>(
        act, w2b, cnt, offs, toklist, wlist, out);
}

// Round 4
// 817.147 us; speedup vs baseline: 1.0438x; 1.0068x over previous
//
#include <hip/hip_runtime.h>
#include <hip/hip_bf16.h>

#define T_TOK 4096
#define DIM   1024
#define FDIM  4096
#define NEXP  8
#define BM    128
#define AM    256
#define AK    32

typedef __attribute__((ext_vector_type(8))) short bf16x8_t;   // 8 bf16 = 4 VGPR
typedef __attribute__((ext_vector_type(4))) float f32x4_t;    // MFMA C/D

// async global->LDS, 16B per lane; LDS dest = wave-uniform base + lane*16
#define GLD16(gp, lp) __builtin_amdgcn_global_load_lds( \
    (const __attribute__((address_space(1))) unsigned int*)(gp), \
    (__attribute__((address_space(3))) unsigned int*)(lp), 16, 0, 0)

__device__ __forceinline__ unsigned short f2bf(float f) {
    union { __hip_bfloat16 h; unsigned short u; } c;
    c.h = __float2bfloat16(f);
    return c.u;
}
__device__ __forceinline__ uint4 pack8(const float4& a, const float4& b) {
    union { unsigned short s[8]; uint4 v; } u;
    u.s[0] = f2bf(a.x); u.s[1] = f2bf(a.y); u.s[2] = f2bf(a.z); u.s[3] = f2bf(a.w);
    u.s[4] = f2bf(b.x); u.s[5] = f2bf(b.y); u.s[6] = f2bf(b.z); u.s[7] = f2bf(b.w);
    return u.v;
}

// ---------------------------------------------------------------------------
// 0. fp32 -> bf16 streaming convert (8 elems/thread)
// ---------------------------------------------------------------------------
__global__ __launch_bounds__(256) void convert_kernel(
    const float* __restrict__ src, unsigned short* __restrict__ dst, int n8)
{
    int i = blockIdx.x * 256 + threadIdx.x;
    if (i < n8) {
        const float4* s = reinterpret_cast<const float4*>(src) + (size_t)i * 2;
        float4 a = s[0], b = s[1];
        reinterpret_cast<uint4*>(dst)[i] = pack8(a, b);
    }
}

// ---------------------------------------------------------------------------
// 1. Gate: one wave per token. fp32 logits, top-2, renormalized weights.
//    Records per-token (expert, pos, weight) pairs for the combine kernel.
// ---------------------------------------------------------------------------
__global__ __launch_bounds__(256) void gate_kernel(
    const float* __restrict__ x, const float* __restrict__ gw,
    const float* __restrict__ gb, int* __restrict__ cnt,
    int* __restrict__ toklist, int* __restrict__ tokexp,
    int* __restrict__ tokpos, float* __restrict__ tokwt)
{
    const int lane = threadIdx.x & 63;
    const int wv   = threadIdx.x >> 6;
    const int t    = blockIdx.x * 4 + wv;
    const float* xr = x + (size_t)t * DIM;

    float4 xv[4];
#pragma unroll
    for (int c = 0; c < 4; ++c)
        xv[c] = *reinterpret_cast<const float4*>(xr + c * 256 + lane * 4);

    float logit[NEXP];
#pragma unroll
    for (int e = 0; e < NEXP; ++e) {
        const float* gr = gw + e * DIM;
        float s = 0.f;
#pragma unroll
        for (int c = 0; c < 4; ++c) {
            float4 g = *reinterpret_cast<const float4*>(gr + c * 256 + lane * 4);
            s += xv[c].x * g.x + xv[c].y * g.y + xv[c].z * g.z + xv[c].w * g.w;
        }
#pragma unroll
        for (int o = 32; o > 0; o >>= 1) s += __shfl_xor(s, o, 64);
        logit[e] = s + gb[e];
    }

    if (lane == 0) {
        int i1 = 0;
#pragma unroll
        for (int e = 1; e < NEXP; ++e) if (logit[e] > logit[i1]) i1 = e;
        int i2 = (i1 == 0) ? 1 : 0;
#pragma unroll
        for (int e = 0; e < NEXP; ++e)
            if (e != i1 && e != i2 && logit[e] > logit[i2]) i2 = e;
        float eb = expf(logit[i2] - logit[i1]);
        float wA = 1.f / (1.f + eb);
        float wB = eb / (1.f + eb);
        int p = atomicAdd(&cnt[i1], 1);
        toklist[i1 * T_TOK + p] = t;
        tokexp[2 * t] = i1; tokpos[2 * t] = p; tokwt[2 * t] = wA;
        p = atomicAdd(&cnt[i2], 1);
        toklist[i2 * T_TOK + p] = t;
        tokexp[2 * t + 1] = i2; tokpos[2 * t + 1] = p; tokwt[2 * t + 1] = wB;
    }
}

// ---------------------------------------------------------------------------
// 2. 256-aligned exclusive prefix of per-expert counts
// ---------------------------------------------------------------------------
__global__ void offsets_kernel(const int* __restrict__ cnt, int* __restrict__ offs)
{
    if (threadIdx.x == 0) {
        int o = 0;
#pragma unroll
        for (int e = 0; e < NEXP; ++e) {
            offs[e] = o;
            o += ((cnt[e] + AM - 1) / AM) * AM;
        }
    }
}

// ---------------------------------------------------------------------------
// 3. Stage A: fused h1/h3 GEMM + SwiGLU -> act (bf16)   [UNCHANGED]
// ---------------------------------------------------------------------------
#define ASTEP(TC, AFC, AFN, PF, RDNEXT, VM)                                    \
  {                                                                            \
    const unsigned short* bufc_ = lds + ((TC) & 3) * 16384;                    \
    bf16x8_t b1a_ = *reinterpret_cast<const bf16x8_t*>(bufc_ + 8192  + wnn * 1024 + swz);       \
    bf16x8_t b1b_ = *reinterpret_cast<const bf16x8_t*>(bufc_ + 8192  + wnn * 1024 + 512 + swz); \
    bf16x8_t b3a_ = *reinterpret_cast<const bf16x8_t*>(bufc_ + 12288 + wnn * 1024 + swz);       \
    bf16x8_t b3b_ = *reinterpret_cast<const bf16x8_t*>(bufc_ + 12288 + wnn * 1024 + 512 + swz); \
    if (RDNEXT) {                                                              \
      const unsigned short* bufn_ = lds + (((TC) + 1) & 3) * 16384 + wm * 4096 + swz; \
      _Pragma("unroll")                                                        \
      for (int i_ = 0; i_ < 8; ++i_)                                           \
        AFN[i_] = *reinterpret_cast<const bf16x8_t*>(bufn_ + i_ * 512);        \
    }                                                                          \
    __builtin_amdgcn_sched_barrier(0);                                         \
    if (PF) {                                                                  \
      const int pb_ = ((TC) + 3) & 3;                                          \
      GLD16(Ag0 + ((TC) + 3) * AK, lds + pb_ * 16384 + wv * 512);              \
      GLD16(Ag1 + ((TC) + 3) * AK, lds + pb_ * 16384 + (wv + 8) * 512);        \
      GLD16(B1g + ((TC) + 3) * AK, lds + pb_ * 16384 + 8192 + wv * 512);       \
      GLD16(B3g + ((TC) + 3) * AK, lds + pb_ * 16384 + 12288 + wv * 512);      \
    }                                                                          \
    __builtin_amdgcn_s_setprio(1);                                             \
    _Pragma("unroll")                                                          \
    for (int i_ = 0; i_ < 8; ++i_) {                                           \
      acc1[i_][0] = __builtin_amdgcn_mfma_f32_16x16x32_bf16(AFC[i_], b1a_, acc1[i_][0], 0, 0, 0); \
      acc1[i_][1] = __builtin_amdgcn_mfma_f32_16x16x32_bf16(AFC[i_], b1b_, acc1[i_][1], 0, 0, 0); \
      acc3[i_][0] = __builtin_amdgcn_mfma_f32_16x16x32_bf16(AFC[i_], b3a_, acc3[i_][0], 0, 0, 0); \
      acc3[i_][1] = __builtin_amdgcn_mfma_f32_16x16x32_bf16(AFC[i_], b3b_, acc3[i_][1], 0, 0, 0); \
    }                                                                          \
    __builtin_amdgcn_s_setprio(0);                                             \
    asm volatile("s_waitcnt " VM ::: "memory");                                \
    __builtin_amdgcn_s_barrier();                                              \
  }

__global__ __launch_bounds__(512, 2) void stageA_kernel(
    const unsigned short* __restrict__ xb, const unsigned short* __restrict__ w1b,
    const unsigned short* __restrict__ w3b, const int* __restrict__ cnt,
    const int* __restrict__ offs, const int* __restrict__ toklist,
    const unsigned short* __restrict__ zbuf, unsigned short* __restrict__ act)
{
    const int e  = blockIdx.z;
    const int c  = cnt[e];
    const int mt = blockIdx.y;
    if (mt * AM >= c) return;
    const int nt = blockIdx.x;               // 0..31: 128-col group of F
    const int n0 = nt * 128;

    __shared__ __align__(16) unsigned short lds[4 * 16384];  // 128 KB static

    const int tid  = threadIdx.x;
    const int lane = tid & 63;
    const int wv   = tid >> 6;               // 0..7
    const int wm   = wv >> 2;                // 0..1: 128-row half
    const int wnn  = wv & 3;                 // 0..3: 32-col group
    const int quad = lane >> 4;
    const int r    = lane & 15;

    const int swz = (r * 32 + quad * 8) ^ (((r >> 1) & 3) << 3);
    const int wr = (lane >> 2) & 15;
    const int wc = (((lane ^ (lane >> 3)) & 1) << 3) |
                   ((((lane >> 1) ^ (lane >> 4)) & 1) << 4);

    const int stRow = wv * 16 + wr;          // 0..127
    const int ar0 = mt * AM + stRow;
    const int ar1 = ar0 + 128;
    const unsigned short* Ag0 = (ar0 < c)
        ? xb + (size_t)toklist[e * T_TOK + ar0] * DIM + wc : zbuf + wc;
    const unsigned short* Ag1 = (ar1 < c)
        ? xb + (size_t)toklist[e * T_TOK + ar1] * DIM + wc : zbuf + wc;
    const unsigned short* B1g = w1b + ((size_t)e * FDIM + n0 + stRow) * DIM + wc;
    const unsigned short* B3g = w3b + ((size_t)e * FDIM + n0 + stRow) * DIM + wc;

    f32x4_t acc1[8][2], acc3[8][2];
#pragma unroll
    for (int i = 0; i < 8; ++i)
#pragma unroll
        for (int j = 0; j < 2; ++j) {
            acc1[i][j] = (f32x4_t){0.f, 0.f, 0.f, 0.f};
            acc3[i][j] = (f32x4_t){0.f, 0.f, 0.f, 0.f};
        }

#pragma unroll
    for (int t = 0; t < 3; ++t) {
        GLD16(Ag0 + t * AK, lds + t * 16384 + wv * 512);
        GLD16(Ag1 + t * AK, lds + t * 16384 + (wv + 8) * 512);
        GLD16(B1g + t * AK, lds + t * 16384 + 8192 + wv * 512);
        GLD16(B3g + t * AK, lds + t * 16384 + 12288 + wv * 512);
    }
    asm volatile("s_waitcnt vmcnt(4)" ::: "memory");   // tiles 0,1 landed
    __builtin_amdgcn_s_barrier();

    bf16x8_t afA[8], afB[8];
    {
        const unsigned short* b0 = lds + wm * 4096 + swz;
#pragma unroll
        for (int i = 0; i < 8; ++i)
            afA[i] = *reinterpret_cast<const bf16x8_t*>(b0 + i * 512);
    }

#pragma unroll 1
    for (int t = 0; t < 28; t += 2) {
        ASTEP(t,     afA, afB, 1, 1, "vmcnt(4)");
        ASTEP(t + 1, afB, afA, 1, 1, "vmcnt(4)");
    }
    ASTEP(28, afA, afB, 1, 1, "vmcnt(4)");
    ASTEP(29, afB, afA, 0, 1, "vmcnt(0)");
    ASTEP(30, afA, afB, 0, 1, "vmcnt(0)");
    ASTEP(31, afB, afA, 0, 0, "vmcnt(0)");

    const size_t slot0 = (size_t)offs[e] + (size_t)mt * AM;
    unsigned short* abase = act + (slot0 + wm * 128 + quad * 4) * (size_t)FDIM
                          + n0 + wnn * 32 + r;
#pragma unroll
    for (int i = 0; i < 8; ++i)
#pragma unroll
        for (int j = 0; j < 2; ++j)
#pragma unroll
            for (int rr = 0; rr < 4; ++rr) {
                float h1 = acc1[i][j][rr];
                float h3 = acc3[i][j][rr];
                float sw = h1 / (1.f + __expf(-h1)) * h3;
                abase[(size_t)(i * 16 + rr) * FDIM + j * 16] = f2bf(sw);
            }
}

// ---------------------------------------------------------------------------
// 4. Stage B: Yp[slot] = act[slot] @ w2[e]^T   (no atomics, no K-split)
//    Pipelined like stageA: BM=128 rows x dual 128-col halves (n0, n0+512),
//    BK=32, 128 K-steps, 4 LDS buffers (96 KB), XOR swizzle, vmcnt(3),
//    register-double-buffered A-frags, 1 barrier/K-step.
// ---------------------------------------------------------------------------
// LDS buffer (shorts), per buffer of 12288 (24 KB):
//   A  : 8 subtiles (16 rows x 32 k, 512 shorts) @ 0
//   B1 : 8 subtiles (cols n0..n0+128)            @ 4096
//   B3 : 8 subtiles (cols n0+512..n0+640)        @ 8192

#define BSTEP(TC, AFC, AFN, PF, RDNEXT, VM)                                    \
  {                                                                            \
    const unsigned short* bufc_ = ldsB + ((TC) & 3) * 12288;                   \
    bf16x8_t b1a_ = *reinterpret_cast<const bf16x8_t*>(bufc_ + 4096 + wnn * 1024 + swz);       \
    bf16x8_t b1b_ = *reinterpret_cast<const bf16x8_t*>(bufc_ + 4096 + wnn * 1024 + 512 + swz); \
    bf16x8_t b3a_ = *reinterpret_cast<const bf16x8_t*>(bufc_ + 8192 + wnn * 1024 + swz);       \
    bf16x8_t b3b_ = *reinterpret_cast<const bf16x8_t*>(bufc_ + 8192 + wnn * 1024 + 512 + swz); \
    if (RDNEXT) {                                                              \
      const unsigned short* bufn_ = ldsB + (((TC) + 1) & 3) * 12288 + wm * 2048 + swz; \
      _Pragma("unroll")                                                        \
      for (int i_ = 0; i_ < 4; ++i_)                                           \
        AFN[i_] = *reinterpret_cast<const bf16x8_t*>(bufn_ + i_ * 512);        \
    }                                                                          \
    __builtin_amdgcn_sched_barrier(0);                                         \
    if (PF) {                                                                  \
      const int pb_ = ((TC) + 3) & 3;                                          \
      GLD16(Adma  + ((TC) + 3) * AK, ldsB + pb_ * 12288 + wv * 512);           \
      GLD16(B1dma + ((TC) + 3) * AK, ldsB + pb_ * 12288 + 4096 + wv * 512);    \
      GLD16(B3dma + ((TC) + 3) * AK, ldsB + pb_ * 12288 + 8192 + wv * 512);    \
    }                                                                          \
    __builtin_amdgcn_s_setprio(1);                                             \
    _Pragma("unroll")                                                          \
    for (int i_ = 0; i_ < 4; ++i_) {                                           \
      acc1[i_][0] = __builtin_amdgcn_mfma_f32_16x16x32_bf16(AFC[i_], b1a_, acc1[i_][0], 0, 0, 0); \
      acc1[i_][1] = __builtin_amdgcn_mfma_f32_16x16x32_bf16(AFC[i_], b1b_, acc1[i_][1], 0, 0, 0); \
      acc3[i_][0] = __builtin_amdgcn_mfma_f32_16x16x32_bf16(AFC[i_], b3a_, acc3[i_][0], 0, 0, 0); \
      acc3[i_][1] = __builtin_amdgcn_mfma_f32_16x16x32_bf16(AFC[i_], b3b_, acc3[i_][1], 0, 0, 0); \
    }                                                                          \
    __builtin_amdgcn_s_setprio(0);                                             \
    asm volatile("s_waitcnt " VM ::: "memory");                                \
    __builtin_amdgcn_s_barrier();                                              \
  }

__global__ __launch_bounds__(512, 2) void stageB_kernel(
    const unsigned short* __restrict__ act, const unsigned short* __restrict__ w2b,
    const int* __restrict__ cnt, const int* __restrict__ offs,
    float* __restrict__ Yp)
{
    const int e  = blockIdx.z;
    const int c  = cnt[e];
    const int mt = blockIdx.y;
    if (mt * BM >= c) return;
    const int nt = blockIdx.x;               // 0..3: 128-col group in each half
    const int n0 = nt * 128;
    const size_t slot0 = (size_t)offs[e] + (size_t)mt * BM;

    __shared__ __align__(16) unsigned short ldsB[4 * 12288];  // 96 KB static

    const int tid  = threadIdx.x;
    const int lane = tid & 63;
    const int wv   = tid >> 6;               // 0..7
    const int wm   = wv >> 2;                // 0..1: 64-row half
    const int wnn  = wv & 3;                 // 0..3: 32-col group
    const int quad = lane >> 4;
    const int r    = lane & 15;

    const int swz = (r * 32 + quad * 8) ^ (((r >> 1) & 3) << 3);
    const int wr = (lane >> 2) & 15;
    const int wc = (((lane ^ (lane >> 3)) & 1) << 3) |
                   ((((lane >> 1) ^ (lane >> 4)) & 1) << 4);

    const int stRow = wv * 16 + wr;          // 0..127
    const unsigned short* Adma  = act + (slot0 + stRow) * (size_t)FDIM + wc;
    const unsigned short* B1dma = w2b + ((size_t)e * DIM + n0 + stRow) * FDIM + wc;
    const unsigned short* B3dma = w2b + ((size_t)e * DIM + n0 + 512 + stRow) * FDIM + wc;

    f32x4_t acc1[4][2], acc3[4][2];
#pragma unroll
    for (int i = 0; i < 4; ++i)
#pragma unroll
        for (int j = 0; j < 2; ++j) {
            acc1[i][j] = (f32x4_t){0.f, 0.f, 0.f, 0.f};
            acc3[i][j] = (f32x4_t){0.f, 0.f, 0.f, 0.f};
        }

    // prologue: stage K-tiles 0..2 (9 GLD16 in flight per wave)
#pragma unroll
    for (int t = 0; t < 3; ++t) {
        GLD16(Adma  + t * AK, ldsB + t * 12288 + wv * 512);
        GLD16(B1dma + t * AK, ldsB + t * 12288 + 4096 + wv * 512);
        GLD16(B3dma + t * AK, ldsB + t * 12288 + 8192 + wv * 512);
    }
    asm volatile("s_waitcnt vmcnt(3)" ::: "memory");   // tiles 0,1 landed
    __builtin_amdgcn_s_barrier();

    bf16x8_t afA[4], afB[4];
    {
        const unsigned short* b0 = ldsB + wm * 2048 + swz;
#pragma unroll
        for (int i = 0; i < 4; ++i)
            afA[i] = *reinterpret_cast<const bf16x8_t*>(b0 + i * 512);
    }

    // 128 K-steps (FDIM/AK); prefetch t+3, steady vmcnt(3), 1 barrier/step
#pragma unroll 1
    for (int t = 0; t < 124; t += 2) {
        BSTEP(t,     afA, afB, 1, 1, "vmcnt(3)");
        BSTEP(t + 1, afB, afA, 1, 1, "vmcnt(3)");
    }
    BSTEP(124, afA, afB, 1, 1, "vmcnt(3)");
    BSTEP(125, afB, afA, 0, 1, "vmcnt(0)");
    BSTEP(126, afA, afB, 0, 1, "vmcnt(0)");
    BSTEP(127, afB, afA, 0, 0, "vmcnt(0)");

    // epilogue: direct f32 stores (no atomics); padded rows write zeros
    float* ybase = Yp + (slot0 + wm * 64 + quad * 4) * (size_t)DIM
                 + n0 + wnn * 32 + r;
#pragma unroll
    for (int i = 0; i < 4; ++i)
#pragma unroll
        for (int j = 0; j < 2; ++j)
#pragma unroll
            for (int rr = 0; rr < 4; ++rr) {
                ybase[(size_t)(i * 16 + rr) * DIM + j * 16]       = acc1[i][j][rr];
                ybase[(size_t)(i * 16 + rr) * DIM + j * 16 + 512] = acc3[i][j][rr];
            }
}

// ---------------------------------------------------------------------------
// 5. Combine: out[t] = w0 * Yp[slot0] + w1 * Yp[slot1]   (coalesced float4)
// ---------------------------------------------------------------------------
__global__ __launch_bounds__(256) void combine_kernel(
    const float* __restrict__ Yp, const int* __restrict__ offs,
    const int* __restrict__ tokexp, const int* __restrict__ tokpos,
    const float* __restrict__ tokwt, float* __restrict__ out)
{
    int i = blockIdx.x * 256 + threadIdx.x;      // T*D/4 total
    int t  = i >> 8;                              // D/4 = 256 float4 per row
    int d4 = i & 255;
    int e0 = tokexp[2 * t],     e1 = tokexp[2 * t + 1];
    int s0 = offs[e0] + tokpos[2 * t];
    int s1 = offs[e1] + tokpos[2 * t + 1];
    float w0 = tokwt[2 * t], w1 = tokwt[2 * t + 1];
    float4 a = reinterpret_cast<const float4*>(Yp)[(size_t)s0 * 256 + d4];
    float4 b = reinterpret_cast<const float4*>(Yp)[(size_t)s1 * 256 + d4];
    float4 o;
    o.x = w0 * a.x + w1 * b.x;
    o.y = w0 * a.y + w1 * b.y;
    o.z = w0 * a.z + w1 * b.z;
    o.w = w0 * a.w + w1 * b.w;
    reinterpret_cast<float4*>(out)[i] = o;
}

// ---------------------------------------------------------------------------
extern "C" void kernel_launch(void* const* d_in, const int* in_sizes, int n_in,
                              void* d_out, int out_size, void* d_ws, size_t ws_size,
                              hipStream_t stream)
{
    (void)in_sizes; (void)n_in; (void)out_size; (void)ws_size;
    const float* x  = (const float*)d_in[0];
    const float* gw = (const float*)d_in[1];
    const float* gb = (const float*)d_in[2];
    const float* w1 = (const float*)d_in[3];
    const float* w3 = (const float*)d_in[4];
    const float* w2 = (const float*)d_in[5];
    float* out = (float*)d_out;

    // ws layout (~294 MB). Yp (f32, 42 MB) ALIASES w1b: w1b is dead after
    // stageA, stageB runs strictly after stageA on the same stream.
    char* ws = (char*)d_ws;
    unsigned short* xb   = (unsigned short*)ws;                        //  8,388,608
    unsigned short* act  = (unsigned short*)(ws + 8388608);            // 83,886,080
    unsigned short* w1b  = (unsigned short*)(ws + 92274688);           // 67,108,864
    unsigned short* w3b  = (unsigned short*)(ws + 159383552);          // 67,108,864
    unsigned short* w2b  = (unsigned short*)(ws + 226492416);          // 67,108,864
    unsigned short* zbuf = (unsigned short*)(ws + 293601280);          //      4,096
    float* Yp = (float*)(ws + 92274688);       // alias of w1b region (42 MB need)
    int*   cnt     = (int*)(ws + 293605376);
    int*   offs    = cnt + 64;
    int*   toklist = cnt + 128;                 // NEXP*T_TOK ints
    int*   tokexp  = toklist + NEXP * T_TOK;    // 2*T ints
    int*   tokpos  = tokexp + 2 * T_TOK;        // 2*T ints
    float* tokwt   = (float*)(tokpos + 2 * T_TOK);  // 2*T floats

    hipMemsetAsync(cnt, 0, 64, stream);
    hipMemsetAsync(zbuf, 0, 4096, stream);

    const int n8 = NEXP * FDIM * DIM / 8;   // 4,194,304 per weight tensor
    convert_kernel<<<n8 / 256, 256, 0, stream>>>(w1, w1b, n8);
    convert_kernel<<<n8 / 256, 256, 0, stream>>>(w3, w3b, n8);
    convert_kernel<<<n8 / 256, 256, 0, stream>>>(w2, w2b, n8);
    convert_kernel<<<(T_TOK * DIM / 8) / 256, 256, 0, stream>>>(x, xb, T_TOK * DIM / 8);

    gate_kernel<<<T_TOK / 4, 256, 0, stream>>>(x, gw, gb, cnt, toklist,
                                               tokexp, tokpos, tokwt);
    offsets_kernel<<<1, 64, 0, stream>>>(cnt, offs);
    stageA_kernel<<<dim3(FDIM / 128, T_TOK / AM, NEXP), 512, 0, stream>>>(
        xb, w1b, w3b, cnt, offs, toklist, zbuf, act);
    stageB_kernel<<<dim3(DIM / 256, T_TOK / BM, NEXP), 512, 0, stream>>>(
        act, w2b, cnt, offs, Yp);
    combine_kernel<<<T_TOK * DIM / 4 / 256, 256, 0, stream>>>(
        Yp, offs, tokexp, tokpos, tokwt, out);
}